// Round 10
// baseline (177.555 us; speedup 1.0000x reference)
//
#include <hip/hip_runtime.h>

// ALayer: out = conv3x3(x, weight*A_w) * sigmoid(conv3x3(relu(conv3x3(x,se_w1)), se_w2))
// B=8, C=256, H=W=56. bf16 MFMA implicit GEMM on NHWC-padded input.
// Round 10: fix epilogue write split. Wave tiling wm=wid>>1 (4x32 rows), wn=wid&1
// (2x64 px = FULL output row per wave) -> no half-line RMW (round 9: +24MB RFO
// fetch, 2x writeback). Schedule unchanged: slab(32K)+A-dbuf(2x16K)=64KB,
// counted vmcnt(2), setprio, fused SE2 epilogue.

typedef unsigned short u16;
typedef __bf16 bf16x8 __attribute__((ext_vector_type(8)));
typedef unsigned short us8 __attribute__((ext_vector_type(8)));
typedef unsigned short us4v __attribute__((ext_vector_type(4)));
typedef float f32x4 __attribute__((ext_vector_type(4)));
typedef float f4v __attribute__((ext_vector_type(4)));

#define HP 58   // padded H/W
#define HW 3136 // 56*56

__device__ __forceinline__ u16 f2bf(float f) {
  unsigned u = __float_as_uint(f);
  u = (u + 0x7fffu + ((u >> 16) & 1u)) >> 16;  // RNE, inputs finite
  return (u16)u;
}
__device__ __forceinline__ float bf2f(u16 v) {
  return __uint_as_float(((unsigned)v) << 16);
}

// async global->LDS, 16B per lane. LDS dest is wave-uniform base + lane*16.
__device__ __forceinline__ void gload16(const u16* g, u16* l) {
  __builtin_amdgcn_global_load_lds((const __attribute__((address_space(1))) void*)g,
                                   (__attribute__((address_space(3))) void*)l,
                                   16, 0, 0);
}

// ---------- k_pre: fused transform (NCHW f32 -> padded NHWC bf16) + weight prep
// + border zeroing. Grid 896.
__global__ __launch_bounds__(256) void k_pre(const float* __restrict__ x,
                                             const float* __restrict__ weight,
                                             const float* __restrict__ A_w,
                                             const float* __restrict__ se_w1,
                                             u16* __restrict__ xp, u16* __restrict__ wb,
                                             u16* __restrict__ w1b, u16* __restrict__ se1p) {
  __shared__ __align__(16) u16 trans[56 * 72];
  const int bid = blockIdx.x;
  const int t = threadIdx.x;
  if (bid < 448) {
    const int h = bid % 56, b = bid / 56;
    if (t < 64) {
      int half = t >> 5, seg = t & 31;
      us8 z8 = {};
      *(us8*)(xp + ((size_t)((b * HP + h + 1) * HP + half * 57)) * 256 + seg * 8) = z8;
    }
    for (int cc = 0; cc < 4; ++cc) {
      const int c0 = cc * 64;
#pragma unroll
      for (int i = 0; i < 4; ++i) {
        int idx = t + 256 * i;
        if (idx < 896) {
          int ci = idx / 14, s = idx % 14;
          f4v v = *(const f4v*)(x + ((size_t)(b * 256 + c0 + ci)) * HW + h * 56 + s * 4);
#pragma unroll
          for (int j = 0; j < 4; ++j) trans[(s * 4 + j) * 72 + ci] = f2bf(v[j]);
        }
      }
      __syncthreads();
#pragma unroll
      for (int i = 0; i < 2; ++i) {
        int idx = t + 256 * i;
        if (idx < 448) {
          int w = idx >> 3, seg = idx & 7;
          us8 v = *(const us8*)&trans[w * 72 + seg * 8];
          *(us8*)(xp + ((size_t)((b * HP + h + 1) * HP + (w + 1))) * 256 + c0 + seg * 8) = v;
        }
      }
      __syncthreads();
    }
  } else if (bid < 704) {
    int idx = (bid - 448) * 256 + t;  // (o,c) pair
    int o = idx >> 8, c = idx & 255;
    const float* wsrc = weight + (size_t)idx * 9;
    const float* asrc = A_w + c * 9;
#pragma unroll
    for (int tap = 0; tap < 9; ++tap)
      wb[tap * 65536 + o * 256 + c] = f2bf(wsrc[tap] * asrc[tap]);
  } else if (bid < 720) {
    int idx = (bid - 704) * 256 + t;  // (o,c), o<16
    if (idx < 4096) {
      const float* wsrc = se_w1 + (size_t)idx * 9;
#pragma unroll
      for (int tap = 0; tap < 9; ++tap)
        w1b[tap * 4096 + idx] = f2bf(wsrc[tap]);
    }
  } else {
    int zid = (bid - 720) * 256 + t;  // 0..45055
    us8 z8 = {};
#pragma unroll
    for (int j = 0; j < 2; ++j) {
      int ch = zid + j * 45056;
      if (ch < 29696) {  // xp rows 0 and 57, all b
        int b = ch / 3712; int rem = ch - b * 3712;
        int row = (rem < 1856) ? 0 : 57;
        int r2 = (rem < 1856) ? rem : rem - 1856;
        int col = r2 >> 5, seg = r2 & 31;
        *(us8*)(xp + ((size_t)((b * HP + row) * HP + col)) * 256 + seg * 8) = z8;
      } else if (ch < 29696 + 53824) {  // all of se1p
        int c2 = ch - 29696;
        *(us8*)(se1p + (size_t)c2 * 8) = z8;
      }
    }
  }
}

// ---------- SE conv1 + relu: one output row per block (448 blocks), M=16, N=64.
__global__ __launch_bounds__(256) void k_se1(const u16* __restrict__ xp,
                                             const u16* __restrict__ w1b,
                                             u16* __restrict__ se1p) {
  __shared__ __align__(16) u16 Alds[144 * 64];      // 18432 B, swizzled [row][slot]
  __shared__ __align__(16) u16 slab[3 * 64 * 64];   // 24576 B
  const int t = threadIdx.x;
  const int lane = t & 63;
  const int wv = t >> 6;
  const int l15 = lane & 15, lg = lane >> 4;
  const int wg = blockIdx.x;      // 448: b = XCD
  const int b = wg & 7;
  const int h = wg >> 3;          // output row 0..55

  f32x4 acc = {0.f, 0.f, 0.f, 0.f};

  for (int cc = 0; cc < 4; ++cc) {
    const int c0 = cc * 64;
    __syncthreads();
    for (int idx = t; idx < 1152; idx += 256) {
      int row = idx >> 3, seg = idx & 7;
      us8 v = *(const us8*)(w1b + ((size_t)(row / 16) * 4096 + (row & 15) * 256 + c0 + seg * 8));
      *(us8*)&Alds[row * 64 + (seg ^ (row & 7)) * 8] = v;
    }
#pragma unroll
    for (int i = 0; i < 6; ++i) {
      int chunk = i * 256 + t;
      int row = chunk >> 9, col = (chunk >> 3) & 63, seg = chunk & 7;
      const u16* src = xp + ((size_t)((b * HP + h + row) * HP + col)) * 256 + c0 +
                       ((seg ^ (col & 7)) * 8);
      gload16(src, &slab[(i * 256 + wv * 64) * 8]);
    }
    __syncthreads();
#pragma unroll
    for (int tap = 0; tap < 9; ++tap) {
      const int dh = tap / 3, dw = tap % 3;
#pragma unroll
      for (int kk = 0; kk < 2; ++kk) {
        int arow = tap * 16 + l15;
        bf16x8 af = *(const bf16x8*)&Alds[arow * 64 + (((kk * 4 + lg) ^ (arow & 7))) * 8];
        int col = ((wv * 16 + l15) + dw) & 63;
        bf16x8 bfr = *(const bf16x8*)&slab[((dh * 64 + col) * 8 + ((kk * 4 + lg) ^ (col & 7))) * 8];
        acc = __builtin_amdgcn_mfma_f32_16x16x32_bf16(af, bfr, acc, 0, 0, 0);
      }
    }
  }
  int w = wv * 16 + l15;
  if (w < 56) {
    us4v pk;
#pragma unroll
    for (int reg = 0; reg < 4; ++reg) {
      float v = acc[reg];
      v = v > 0.f ? v : 0.f;
      pk[reg] = f2bf(v);
    }
    *(us4v*)(se1p + ((size_t)((b * HP + h + 1) * HP + (w + 1))) * 16 + lg * 4) = pk;
  }
}

// ---------- main conv: BM=128, BN=128 (2 rows x 64), 8 waves (4M x 2N), LDS 64KB.
// Full output row per wave (wn*64 + nt*16 + l15): no half-line RMW writes.
// slab resident per cc (9 taps read shifted); A double-buffered via gload_lds
// with counted vmcnt(2). Fused SE2+sigmoid epilogue (overlay).
__global__ __launch_bounds__(512, 4) void k_main(const u16* __restrict__ xp,
                                                 const u16* __restrict__ wb,
                                                 const u16* __restrict__ se1p,
                                                 const float* __restrict__ se_w2,
                                                 float* __restrict__ out) {
  __shared__ __align__(16) u16 S[32768];  // 65536 B total
  u16* slab = S;                 // 16384 u16 = 32KB : [4 rows][64 cols][8 slots][8]
  u16* Albuf0 = S + 16384;       // 2 x 8KB halves: [128 rows][8 slots][8]
  float* w2s    = (float*)S;          // epilogue overlay (slab dead by then)
  float* amap_s = (float*)(S + 512);  // byte offset 1024
  const int t = threadIdx.x;
  const int lane = t & 63;
  const int wid = t >> 6;           // 0..7
  const int wm = wid >> 1;          // 0..3 : 32 out-channels each
  const int wn = wid & 1;           // 0..1 : 64 pixels = full row
  const int l15 = lane & 15, lg = lane >> 4;
  const int lrow = lane >> 3, lseg = lane & 7;
  // XCD swizzle: 448 blocks, 56 per XCD -> each XCD owns one batch b
  const int wg = blockIdx.x;
  const int b = wg & 7;
  const int rem = wg >> 3;          // 0..55
  const int h0 = (rem >> 1) * 2;
  const int mbase = (rem & 1) * 128;

  f32x4 acc[2][4];
#pragma unroll
  for (int mt = 0; mt < 2; ++mt)
#pragma unroll
    for (int nt = 0; nt < 4; ++nt) {
      f32x4 z = {0.f, 0.f, 0.f, 0.f};
      acc[mt][nt] = z;
    }

  auto stage_slab = [&](int cc) {
    const int c0 = cc * 64;
#pragma unroll
    for (int i = 0; i < 4; ++i) {
      int chunk = wid * 256 + i * 64 + lane;
      int row = chunk >> 9, col = (chunk >> 3) & 63, seg = chunk & 7;
      const u16* src = xp + ((size_t)((b * HP + h0 + row) * HP + col)) * 256 + c0 +
                       ((seg ^ (col & 7)) * 8);
      gload16(src, &slab[(wid * 256 + i * 64) * 8]);
    }
  };
  auto stage_A = [&](int tap, int cc, int buf) {
    const int c0 = cc * 64;
    u16* dst = Albuf0 + buf * 8192;
#pragma unroll
    for (int i = 0; i < 2; ++i) {
      int li = wid * 2 + i;          // 0..15
      int row = li * 8 + lrow;       // 0..127
      const u16* src = wb + ((size_t)(tap * 256 + mbase + row)) * 256 + c0 +
                       ((lseg ^ (row & 7)) * 8);
      gload16(src, &dst[li * 512]);
    }
  };

  stage_slab(0);
  stage_A(0, 0, 0);   // 6 loads/thread outstanding
  int pb = 0;
  for (int cc = 0; cc < 4; ++cc) {
#pragma unroll
    for (int tap = 0; tap < 9; ++tap) {
      if (tap < 8) {
        stage_A(tap + 1, cc, pb ^ 1);
        asm volatile("s_waitcnt vmcnt(2)" ::: "memory");  // this tap's data landed
      } else {
        asm volatile("s_waitcnt vmcnt(0)" ::: "memory");
      }
      __builtin_amdgcn_s_barrier();
      __builtin_amdgcn_sched_barrier(0);
      const int dh = tap / 3, dw = tap % 3;
      const u16* Ab = Albuf0 + pb * 8192;
      __builtin_amdgcn_s_setprio(1);
#pragma unroll
      for (int kk = 0; kk < 2; ++kk) {
        bf16x8 af[2], bfr[4];
#pragma unroll
        for (int mt = 0; mt < 2; ++mt) {
          int row = wm * 32 + mt * 16 + l15;
          af[mt] = *(const bf16x8*)&Ab[row * 64 + (((kk * 4 + lg) ^ (row & 7))) * 8];
        }
#pragma unroll
        for (int nt = 0; nt < 4; ++nt) {
          int p = wn * 64 + nt * 16 + l15;
          int r = (p >> 6) + dh;
          int col = ((p & 63) + dw) & 63;
          bfr[nt] = *(const bf16x8*)&slab[((r * 64 + col) * 8 + ((kk * 4 + lg) ^ (col & 7))) * 8];
        }
#pragma unroll
        for (int mt = 0; mt < 2; ++mt)
#pragma unroll
          for (int nt = 0; nt < 4; ++nt)
            acc[mt][nt] = __builtin_amdgcn_mfma_f32_16x16x32_bf16(af[mt], bfr[nt], acc[mt][nt], 0, 0, 0);
      }
      __builtin_amdgcn_s_setprio(0);
      __builtin_amdgcn_sched_barrier(0);  // all LDS reads before end barrier
      __builtin_amdgcn_s_barrier();
      if (tap == 8 && cc < 3) {
        stage_slab(cc + 1);            // safe: everyone passed the read barrier
        stage_A(0, cc + 1, pb ^ 1);    // 6 outstanding into next phase
      }
      pb ^= 1;
    }
  }

  // fused SE2 + sigmoid (LDS overlay on dead slab area)
  if (t < 144) w2s[t] = se_w2[t];
  __syncthreads();
  if (t < 112) {
    int r = t / 56, w = t - r * 56;
    int h = h0 + r;
    float s = 0.f;
    for (int dh2 = 0; dh2 < 3; ++dh2) {
#pragma unroll
      for (int dw2 = 0; dw2 < 3; ++dw2) {
        const u16* src = se1p + ((size_t)((b * HP + h + dh2) * HP + (w + dw2))) * 16;
        us8 v0 = *(const us8*)src;
        us8 v1 = *(const us8*)(src + 8);
        int tap = dh2 * 3 + dw2;
#pragma unroll
        for (int ci = 0; ci < 8; ++ci) s += bf2f(v0[ci]) * w2s[ci * 9 + tap];
#pragma unroll
        for (int ci = 0; ci < 8; ++ci) s += bf2f(v1[ci]) * w2s[(8 + ci) * 9 + tap];
      }
    }
    amap_s[t] = 1.f / (1.f + expf(-s));
  }
  __syncthreads();
  // epilogue: multiply by attention map, store NCHW fp32 (full row per wave)
#pragma unroll
  for (int nt = 0; nt < 4; ++nt) {
    int n = wn * 64 + nt * 16 + l15;
    int r = n >> 6, w = n & 63;
    if (w < 56) {
      float av = amap_s[r * 56 + w];
#pragma unroll
      for (int mt = 0; mt < 2; ++mt) {
        int obase = mbase + wm * 32 + mt * 16 + lg * 4;
#pragma unroll
        for (int reg = 0; reg < 4; ++reg) {
          out[((size_t)(b * 256 + obase + reg) * 56 + h0 + r) * 56 + w] = acc[mt][nt][reg] * av;
        }
      }
    }
  }
}

extern "C" void kernel_launch(void* const* d_in, const int* in_sizes, int n_in,
                              void* d_out, int out_size, void* d_ws, size_t ws_size,
                              hipStream_t stream) {
  const float* x      = (const float*)d_in[0];
  const float* weight = (const float*)d_in[1];
  const float* A_w    = (const float*)d_in[2];
  const float* se_w1  = (const float*)d_in[3];
  const float* se_w2  = (const float*)d_in[4];
  float* out = (float*)d_out;

  char* ws = (char*)d_ws;
  u16* xp   = (u16*)ws;                    // [8][58][58][256] bf16
  u16* se1p = (u16*)(ws + 13778944);       // [8][58][58][16]  bf16
  u16* wb   = (u16*)(ws + 14640128);       // [9][256][256]    bf16
  u16* w1b  = (u16*)(ws + 15819776);       // [9][16][256]     bf16

  k_pre<<<dim3(896), dim3(256), 0, stream>>>(x, weight, A_w, se_w1, xp, wb, w1b, se1p);
  k_se1<<<dim3(448), dim3(256), 0, stream>>>(xp, w1b, se1p);
  k_main<<<dim3(448), dim3(512), 0, stream>>>(xp, wb, se1p, se_w2, out);
}